// Round 1
// baseline (2782.538 us; speedup 1.0000x reference)
//
#include <hip/hip_runtime.h>

typedef __attribute__((ext_vector_type(8))) short short8;
typedef __attribute__((ext_vector_type(4))) float f32x4;

#define CDIM 512
#define NSEQ 16384

__device__ __forceinline__ unsigned short f2bf(float f) {
    unsigned u = __float_as_uint(f);
    unsigned r = ((u >> 16) & 1u) + 0x7fffu;
    return (unsigned short)((u + r) >> 16);
}

__device__ __forceinline__ void gll16(const void* g, void* l) {
    __builtin_amdgcn_global_load_lds((const __attribute__((address_space(1))) unsigned int*)g,
                                     (__attribute__((address_space(3))) unsigned int*)l,
                                     16, 0, 0);
}

// ---------------------------------------------------------------------------
// Build augmented G = [I + A | I - A], A = W - W^T.  G: 512 rows x 1024 cols.
// ---------------------------------------------------------------------------
__global__ void buildG_kernel(const float* __restrict__ W, float* __restrict__ G) {
    int r = blockIdx.x;
    for (int c = threadIdx.x; c < 1024; c += 256) {
        float v;
        if (c < 512) {
            float a = W[r * 512 + c] - W[c * 512 + r];
            v = (c == r ? 1.f : 0.f) + a;
        } else {
            int c2 = c - 512;
            float a = W[r * 512 + c2] - W[c2 * 512 + r];
            v = (c2 == r ? 1.f : 0.f) - a;
        }
        G[(size_t)r * 1024 + c] = v;
    }
}

// ---------------------------------------------------------------------------
// Invert 128x128 diagonal block via register-resident Gauss-Jordan.
// ---------------------------------------------------------------------------
__global__ __launch_bounds__(512) void invdiag_kernel(float* __restrict__ G,
                                                      float* __restrict__ Dinv, int k) {
    int ck = k * 128;
    __shared__ float prow[2][256];
    __shared__ float pcol[2][128];
    int t = threadIdx.x;
    int c0 = t & 63, rg = t >> 6;
    float rgs[16][4];
#pragma unroll
    for (int m = 0; m < 16; m++) {
        int r = rg + 8 * m;
#pragma unroll
        for (int q = 0; q < 4; q++) {
            int c = c0 + 64 * q;
            rgs[m][q] = (c < 128) ? G[(size_t)(ck + r) * 1024 + ck + c]
                                  : ((r == c - 128) ? 1.f : 0.f);
        }
    }
    if (rg == 0) {
#pragma unroll
        for (int q = 0; q < 4; q++) prow[0][c0 + 64 * q] = rgs[0][q];
    }
    if (c0 == 0) {
#pragma unroll
        for (int m = 0; m < 16; m++) pcol[0][rg + 8 * m] = rgs[m][0];
    }
    __syncthreads();
    for (int p = 0; p < 128; p++) {
        int buf = p & 1;
        float inv = 1.0f / prow[buf][p];
        float pr[4];
#pragma unroll
        for (int q = 0; q < 4; q++) pr[q] = prow[buf][c0 + 64 * q];
#pragma unroll
        for (int m = 0; m < 16; m++) {
            int r = rg + 8 * m;
            if (r == p) {
#pragma unroll
                for (int q = 0; q < 4; q++) rgs[m][q] = pr[q] * inv;
            } else {
                float f = pcol[buf][r] * inv;
#pragma unroll
                for (int q = 0; q < 4; q++) rgs[m][q] -= f * pr[q];
            }
        }
        if (p < 127) {
            int p2 = p + 1, nb = p2 & 1;
            int mp = p2 >> 3, qp = p2 >> 6;
            if (rg == (p2 & 7)) {
#pragma unroll
                for (int m = 0; m < 16; m++)
                    if (m == mp) {
#pragma unroll
                        for (int q = 0; q < 4; q++) prow[nb][c0 + 64 * q] = rgs[m][q];
                    }
            }
            if (c0 == (p2 & 63)) {
#pragma unroll
                for (int q = 0; q < 4; q++)
                    if (q == qp) {
#pragma unroll
                        for (int m = 0; m < 16; m++) pcol[nb][rg + 8 * m] = rgs[m][q];
                    }
            }
        }
        __syncthreads();
    }
#pragma unroll
    for (int m = 0; m < 16; m++) {
        Dinv[(rg + 8 * m) * 128 + c0] = rgs[m][2];
        Dinv[(rg + 8 * m) * 128 + c0 + 64] = rgs[m][3];
    }
}

// ---------------------------------------------------------------------------
// Pivot block-row scale: G[Rk, cbase:cbase+64] = Dinv x G[Rk, cbase:cbase+64]
// ---------------------------------------------------------------------------
__global__ void rowscale_kernel(float* __restrict__ G, const float* __restrict__ Dinv,
                                int k) {
    int ck = k * 128;
    int cbase = ck + 128 + blockIdx.x * 64;
    __shared__ float ins[128][64];
    __shared__ float dch[128][33];
    int t = threadIdx.x;
    for (int idx = t; idx < 128 * 64; idx += 256) {
        int r = idx >> 6, c = idx & 63;
        ins[r][c] = G[(size_t)(ck + r) * 1024 + cbase + c];
    }
    int tx = t & 15, ty = t >> 4;
    float acc[8][4];
#pragma unroll
    for (int i = 0; i < 8; i++)
#pragma unroll
        for (int j = 0; j < 4; j++) acc[i][j] = 0.f;
    for (int mc = 0; mc < 4; mc++) {
        __syncthreads();
        for (int idx = t; idx < 128 * 32; idx += 256) {
            int r = idx >> 5, c = idx & 31;
            dch[r][c] = Dinv[r * 128 + mc * 32 + c];
        }
        __syncthreads();
        for (int m2 = 0; m2 < 32; m2++) {
            int mm = mc * 32 + m2;
            float p0 = ins[mm][tx * 4 + 0], p1 = ins[mm][tx * 4 + 1];
            float p2 = ins[mm][tx * 4 + 2], p3 = ins[mm][tx * 4 + 3];
#pragma unroll
            for (int rr = 0; rr < 8; rr++) {
                float d = dch[ty * 8 + rr][m2];
                acc[rr][0] += d * p0;
                acc[rr][1] += d * p1;
                acc[rr][2] += d * p2;
                acc[rr][3] += d * p3;
            }
        }
    }
#pragma unroll
    for (int rr = 0; rr < 8; rr++)
#pragma unroll
        for (int cc = 0; cc < 4; cc++)
            G[(size_t)(ck + ty * 8 + rr) * 1024 + cbase + tx * 4 + cc] = acc[rr][cc];
}

// ---------------------------------------------------------------------------
// Trailing update: G[i, c] -= G[i, ck:ck+128] x G[Rk, c] for i not in Rk.
// ---------------------------------------------------------------------------
__global__ void trailing_kernel(float* __restrict__ G, int k) {
    int ck = k * 128;
    int rb = blockIdx.x * 32;
    if (rb >= ck) rb += 128;
    int cbase = ck + 128 + blockIdx.y * 64;
    __shared__ float Lt[32][129];
    __shared__ float Pt[128][64];
    int t = threadIdx.x;
    for (int idx = t; idx < 32 * 128; idx += 256) {
        int r = idx >> 7, c = idx & 127;
        Lt[r][c] = G[(size_t)(rb + r) * 1024 + ck + c];
    }
    for (int idx = t; idx < 128 * 64; idx += 256) {
        int r = idx >> 6, c = idx & 63;
        Pt[r][c] = G[(size_t)(ck + r) * 1024 + cbase + c];
    }
    __syncthreads();
    int tx = t & 15, ty = t >> 4;
    float acc[2][4];
#pragma unroll
    for (int i = 0; i < 2; i++)
#pragma unroll
        for (int j = 0; j < 4; j++) acc[i][j] = 0.f;
    for (int mm = 0; mm < 128; mm++) {
        float p0 = Pt[mm][tx * 4 + 0], p1 = Pt[mm][tx * 4 + 1];
        float p2 = Pt[mm][tx * 4 + 2], p3 = Pt[mm][tx * 4 + 3];
        float l0 = Lt[ty * 2 + 0][mm], l1 = Lt[ty * 2 + 1][mm];
        acc[0][0] += l0 * p0; acc[0][1] += l0 * p1; acc[0][2] += l0 * p2; acc[0][3] += l0 * p3;
        acc[1][0] += l1 * p0; acc[1][1] += l1 * p1; acc[1][2] += l1 * p2; acc[1][3] += l1 * p3;
    }
#pragma unroll
    for (int rr = 0; rr < 2; rr++)
#pragma unroll
        for (int cc = 0; cc < 4; cc++)
            G[(size_t)(rb + ty * 2 + rr) * 1024 + cbase + tx * 4 + cc] -= acc[rr][cc];
}

// ---------------------------------------------------------------------------
// Convert K (= right half of G) to bf16, row-major 512x512.
// ---------------------------------------------------------------------------
__global__ void cvtK_kernel(const float* __restrict__ G, unsigned short* __restrict__ Kb) {
    int idx = blockIdx.x * 256 + threadIdx.x;
    int e = idx * 4;
    int j = e >> 9, i = e & 511;
    const float* src = G + (size_t)j * 1024 + 512 + i;
    unsigned short* dst = Kb + j * 512 + i;
    float v0 = src[0], v1 = src[1], v2 = src[2], v3 = src[3];
    unsigned p0 = f2bf(v0), p1 = f2bf(v1), p2 = f2bf(v2), p3 = f2bf(v3);
    uint2 pk;
    pk.x = p0 | (p1 << 16);
    pk.y = p2 | (p3 << 16);
    *(uint2*)dst = pk;
}

// ---------------------------------------------------------------------------
// Main GEMM: y[b, j, n] = sum_i K[j,i] x[b,i,n].  Block = all 512 j, 64 n.
// 512 threads = 8 waves; wave w owns j in [64w, 64w+64), mfma 16x16x32 bf16.
//
// v2: - no 128-VGPR cap (launch_bounds(512,2)) -> no scratch spills
//     - K staged via global_load_lds width=16, linear LDS rows of 64 B,
//       bank conflicts broken by pre-swizzling the GLOBAL source address
//       (XOR of 16B blocks: k2 ^= ((row&3)<<4)) + matching XOR on ds_read
//     - double-buffered LDS, ONE barrier per K-step, x prefetched into
//       registers right after the barrier so HBM latency hides under MFMAs
// ---------------------------------------------------------------------------
#define LDX 40  // padded xt row length (bf16 elems)

__global__ __launch_bounds__(512, 2) void gemm_kernel(const float* __restrict__ x,
                                                      const unsigned short* __restrict__ Kb,
                                                      float* __restrict__ y) {
    __shared__ unsigned short kt[2][512 * 32];  // K tiles: 512 j x 32 i (bf16), linear
    __shared__ unsigned short xt[2][64 * LDX];  // x tiles: 64 n x 32 i (bf16), padded
    int t = threadIdx.x;
    int l = t & 63, w = t >> 6;
    int bx = blockIdx.x;
    int b = bx >> 8;
    int n0 = (bx & 255) << 6;
    const float* xb = x + (size_t)b * CDIM * NSEQ + n0;
    float* yb = y + (size_t)b * CDIM * NSEQ + n0;

    int lr = l & 15;
    int q8 = (l >> 4) * 8;  // k-offset (bf16 elems) of this lane's fragment
    int kidx = q8 ^ ((lr & 3) << 3);  // swizzled k-offset for kt reads

    // per-lane swizzled global source for K staging:
    // row = 64w + 16*inst + (l>>2), 16B block (l&3), swizzle ^((row&3)<<4)
    const char* kgl = (const char*)Kb + (size_t)(64 * w + (l >> 2)) * 1024 +
                      (((l & 3) * 16) ^ (((l >> 2) & 3) << 4));

    f32x4 acc[4][4];
#pragma unroll
    for (int i = 0; i < 4; i++)
#pragma unroll
        for (int j = 0; j < 4; j++) acc[i][j] = (f32x4){0.f, 0.f, 0.f, 0.f};

    // ---- prologue: stage s=0 into buffer 0 ----
    {
        unsigned short* kdst = kt[0] + w * 64 * 32;
#pragma unroll
        for (int i = 0; i < 4; i++) gll16(kgl + i * 16384, kdst + i * 16 * 32);
        const float* xs = xb + (size_t)(w * 4) * NSEQ + l;
        uint2 pk;
        pk.x = f2bf(xs[0]) | ((unsigned)f2bf(xs[NSEQ]) << 16);
        pk.y = f2bf(xs[2 * NSEQ]) | ((unsigned)f2bf(xs[3 * NSEQ]) << 16);
        *(uint2*)(xt[0] + l * LDX + w * 4) = pk;
    }

    for (int s = 0; s < 16; s++) {
        const unsigned short* ktc = kt[s & 1];
        const unsigned short* xtc = xt[s & 1];
        __syncthreads();  // drains vmcnt/lgkm: buf[s&1] now fully staged

        // ---- prefetch s+1 (issue early; latency hides under MFMAs) ----
        float v0, v1, v2, v3;
        if (s < 15) {
            unsigned short* kdst = kt[(s + 1) & 1] + w * 64 * 32;
#pragma unroll
            for (int i = 0; i < 4; i++)
                gll16(kgl + (size_t)(s + 1) * 64 + i * 16384, kdst + i * 16 * 32);
            const float* xs = xb + (size_t)((s + 1) * 32 + w * 4) * NSEQ + l;
            v0 = xs[0];
            v1 = xs[NSEQ];
            v2 = xs[2 * NSEQ];
            v3 = xs[3 * NSEQ];
        }

        // ---- compute on buf[s&1] ----
        short8 af[4], bfr[4];
#pragma unroll
        for (int mt = 0; mt < 4; mt++)
            af[mt] = *(const short8*)(ktc + (w * 64 + mt * 16 + lr) * 32 + kidx);
#pragma unroll
        for (int nt = 0; nt < 4; nt++)
            bfr[nt] = *(const short8*)(xtc + (nt * 16 + lr) * LDX + q8);
#pragma unroll
        for (int mt = 0; mt < 4; mt++)
#pragma unroll
            for (int nt = 0; nt < 4; nt++)
                acc[mt][nt] = __builtin_amdgcn_mfma_f32_16x16x32_bf16(af[mt], bfr[nt],
                                                                      acc[mt][nt], 0, 0, 0);

        // ---- late write of prefetched x into the next buffer ----
        if (s < 15) {
            uint2 pk;
            pk.x = f2bf(v0) | ((unsigned)f2bf(v1) << 16);
            pk.y = f2bf(v2) | ((unsigned)f2bf(v3) << 16);
            *(uint2*)(xt[(s + 1) & 1] + l * LDX + w * 4) = pk;
        }
    }

    int qr = (l >> 4) * 4;
#pragma unroll
    for (int mt = 0; mt < 4; mt++)
#pragma unroll
        for (int nt = 0; nt < 4; nt++)
#pragma unroll
            for (int r = 0; r < 4; r++)
                yb[(size_t)(w * 64 + mt * 16 + qr + r) * NSEQ + nt * 16 + lr] =
                    acc[mt][nt][r];
}

// ---------------------------------------------------------------------------
extern "C" void kernel_launch(void* const* d_in, const int* in_sizes, int n_in,
                              void* d_out, int out_size, void* d_ws, size_t ws_size,
                              hipStream_t stream) {
    const float* x = (const float*)d_in[0];
    const float* W = (const float*)d_in[1];
    float* y = (float*)d_out;

    float* G = (float*)d_ws;                                         // 2 MB
    float* DINV = (float*)((char*)d_ws + 0x200000);                  // 64 KB
    unsigned short* KB = (unsigned short*)((char*)d_ws + 0x210000);  // 512 KB

    buildG_kernel<<<512, 256, 0, stream>>>(W, G);
    for (int k = 0; k < 4; k++) {
        invdiag_kernel<<<1, 512, 0, stream>>>(G, DINV, k);
        int ncols = 896 - 128 * k;
        rowscale_kernel<<<ncols / 64, 256, 0, stream>>>(G, DINV, k);
        trailing_kernel<<<dim3(12, ncols / 64), 256, 0, stream>>>(G, k);
    }
    cvtK_kernel<<<256, 256, 0, stream>>>(G, KB);
    gemm_kernel<<<4096, 512, 0, stream>>>(x, KB, y);
}

// Round 2
// 1997.822 us; speedup vs baseline: 1.3928x; 1.3928x over previous
//
#include <hip/hip_runtime.h>
#include <hip/hip_cooperative_groups.h>

namespace cg = cooperative_groups;

typedef __attribute__((ext_vector_type(8))) short short8;
typedef __attribute__((ext_vector_type(4))) float f32x4;

#define CDIM 512
#define NSEQ 16384

__device__ __forceinline__ unsigned short f2bf(float f) {
    unsigned u = __float_as_uint(f);
    unsigned r = ((u >> 16) & 1u) + 0x7fffu;
    return (unsigned short)((u + r) >> 16);
}

__device__ __forceinline__ void gll16(const void* g, void* l) {
    __builtin_amdgcn_global_load_lds((const __attribute__((address_space(1))) unsigned int*)g,
                                     (__attribute__((address_space(3))) unsigned int*)l,
                                     16, 0, 0);
}

// ===========================================================================
// Fused Cayley factorization (cooperative): buildG -> 4x(invdiag, rowscale,
// trailing) -> cvtK, all in one dispatch with grid.sync() between phases.
// Grid: 128 blocks x 512 threads (<=1 block/CU -> co-residency guaranteed).
// ===========================================================================
__global__ __launch_bounds__(512, 1) void cayley_kernel(const float* __restrict__ W,
                                                        float* __restrict__ G,
                                                        float* __restrict__ Dinv,
                                                        float* __restrict__ Pbuf,
                                                        unsigned short* __restrict__ Kb) {
    cg::grid_group gg = cg::this_grid();
    __shared__ union {
        struct { float prow[2][256]; float pcol[2][128]; } inv;
        struct { float ins[128][64]; float dch[128][33]; } rs;
        struct { float Lt[64][129]; float Pt[128][64]; } tr;
    } sm;

    int t = threadIdx.x;
    int bid = blockIdx.x;
    int gtid = bid * 512 + t;

    // ---- phase 0: build augmented G = [I + A | I - A], A = W - W^T ----
    for (int e = gtid; e < 512 * 1024; e += 128 * 512) {
        int r = e >> 10, c = e & 1023;
        float v;
        if (c < 512) {
            float a = W[r * 512 + c] - W[c * 512 + r];
            v = (c == r ? 1.f : 0.f) + a;
        } else {
            int c2 = c - 512;
            float a = W[r * 512 + c2] - W[c2 * 512 + r];
            v = (c2 == r ? 1.f : 0.f) - a;
        }
        G[e] = v;
    }
    gg.sync();

    for (int k = 0; k < 4; k++) {
        int ck = k * 128;
        int nct = (896 - 128 * k) >> 6;  // 64-col tiles in active region

        // ---- phase 1: invert 128x128 diagonal block (block 0 only) ----
        // Register-resident Gauss-Jordan, 512 threads, no pivoting.
        if (bid == 0) {
            int c0 = t & 63, rg = t >> 6;
            float rgs[16][4];
#pragma unroll
            for (int m = 0; m < 16; m++) {
                int r = rg + 8 * m;
#pragma unroll
                for (int q = 0; q < 4; q++) {
                    int c = c0 + 64 * q;
                    rgs[m][q] = (c < 128) ? G[(size_t)(ck + r) * 1024 + ck + c]
                                          : ((r == c - 128) ? 1.f : 0.f);
                }
            }
            if (rg == 0) {
#pragma unroll
                for (int q = 0; q < 4; q++) sm.inv.prow[0][c0 + 64 * q] = rgs[0][q];
            }
            if (c0 == 0) {
#pragma unroll
                for (int m = 0; m < 16; m++) sm.inv.pcol[0][rg + 8 * m] = rgs[m][0];
            }
            __syncthreads();
            for (int p = 0; p < 128; p++) {
                int buf = p & 1;
                float inv = 1.0f / sm.inv.prow[buf][p];
                float pr[4];
#pragma unroll
                for (int q = 0; q < 4; q++) pr[q] = sm.inv.prow[buf][c0 + 64 * q];
#pragma unroll
                for (int m = 0; m < 16; m++) {
                    int r = rg + 8 * m;
                    if (r == p) {
#pragma unroll
                        for (int q = 0; q < 4; q++) rgs[m][q] = pr[q] * inv;
                    } else {
                        float f = sm.inv.pcol[buf][r] * inv;
#pragma unroll
                        for (int q = 0; q < 4; q++) rgs[m][q] -= f * pr[q];
                    }
                }
                if (p < 127) {
                    int p2 = p + 1, nb = p2 & 1;
                    int mp = p2 >> 3, qp = p2 >> 6;
                    if (rg == (p2 & 7)) {
#pragma unroll
                        for (int m = 0; m < 16; m++)
                            if (m == mp) {
#pragma unroll
                                for (int q = 0; q < 4; q++)
                                    sm.inv.prow[nb][c0 + 64 * q] = rgs[m][q];
                            }
                    }
                    if (c0 == (p2 & 63)) {
#pragma unroll
                        for (int q = 0; q < 4; q++)
                            if (q == qp) {
#pragma unroll
                                for (int m = 0; m < 16; m++)
                                    sm.inv.pcol[nb][rg + 8 * m] = rgs[m][q];
                            }
                    }
                }
                __syncthreads();
            }
#pragma unroll
            for (int m = 0; m < 16; m++) {
                Dinv[(rg + 8 * m) * 128 + c0] = rgs[m][2];
                Dinv[(rg + 8 * m) * 128 + c0 + 64] = rgs[m][3];
            }
        }
        gg.sync();

        // ---- phase 2: P = Dinv x G[Rk, active cols] -> Pbuf[128][896] ----
        if (bid < nct) {
            int cbase = ck + 128 + bid * 64;
            for (int idx = t; idx < 128 * 64; idx += 512) {
                int r = idx >> 6, c = idx & 63;
                sm.rs.ins[r][c] = G[(size_t)(ck + r) * 1024 + cbase + c];
            }
            int tx = t & 15, ty = t >> 4;  // ty in 0..31, rows 4*ty+rr
            float acc[4][4];
#pragma unroll
            for (int i = 0; i < 4; i++)
#pragma unroll
                for (int j = 0; j < 4; j++) acc[i][j] = 0.f;
            for (int mc = 0; mc < 4; mc++) {
                __syncthreads();
                for (int idx = t; idx < 128 * 32; idx += 512) {
                    int r = idx >> 5, c = idx & 31;
                    sm.rs.dch[r][c] = Dinv[r * 128 + mc * 32 + c];
                }
                __syncthreads();
                for (int m2 = 0; m2 < 32; m2++) {
                    int mm = mc * 32 + m2;
                    float p0 = sm.rs.ins[mm][tx * 4 + 0], p1 = sm.rs.ins[mm][tx * 4 + 1];
                    float p2 = sm.rs.ins[mm][tx * 4 + 2], p3 = sm.rs.ins[mm][tx * 4 + 3];
#pragma unroll
                    for (int rr = 0; rr < 4; rr++) {
                        float d = sm.rs.dch[ty * 4 + rr][m2];
                        acc[rr][0] += d * p0;
                        acc[rr][1] += d * p1;
                        acc[rr][2] += d * p2;
                        acc[rr][3] += d * p3;
                    }
                }
            }
#pragma unroll
            for (int rr = 0; rr < 4; rr++)
#pragma unroll
                for (int cc = 0; cc < 4; cc++)
                    Pbuf[(ty * 4 + rr) * 896 + bid * 64 + tx * 4 + cc] = acc[rr][cc];
        }
        gg.sync();

        // ---- phase 3: trailing update + pivot-row copy ----
        {
            int ct = bid >> 3, rt = bid & 7;  // 8 row-tiles of 64, nct col-tiles
            if (ct < nct) {
                int cbase = ck + 128 + ct * 64;
                int rb = rt * 64;
                bool pivot = (rb >= ck) && (rb < ck + 128);
                if (pivot) {
                    // G[Rk, cols] = P
                    for (int idx = t; idx < 64 * 64; idx += 512) {
                        int r = idx >> 6, c = idx & 63;
                        G[(size_t)(rb + r) * 1024 + cbase + c] =
                            Pbuf[(rb - ck + r) * 896 + ct * 64 + c];
                    }
                } else {
                    for (int idx = t; idx < 64 * 128; idx += 512) {
                        int r = idx >> 7, c = idx & 127;
                        sm.tr.Lt[r][c] = G[(size_t)(rb + r) * 1024 + ck + c];
                    }
                    for (int idx = t; idx < 128 * 64; idx += 512) {
                        int r = idx >> 6, c = idx & 63;
                        sm.tr.Pt[r][c] = Pbuf[r * 896 + ct * 64 + c];
                    }
                    __syncthreads();
                    int tx = t & 15, ty = t >> 4;  // rows 2*ty, 2*ty+1
                    float acc[2][4];
#pragma unroll
                    for (int i = 0; i < 2; i++)
#pragma unroll
                        for (int j = 0; j < 4; j++) acc[i][j] = 0.f;
                    for (int mm = 0; mm < 128; mm++) {
                        float p0 = sm.tr.Pt[mm][tx * 4 + 0], p1 = sm.tr.Pt[mm][tx * 4 + 1];
                        float p2 = sm.tr.Pt[mm][tx * 4 + 2], p3 = sm.tr.Pt[mm][tx * 4 + 3];
                        float l0 = sm.tr.Lt[ty * 2 + 0][mm], l1 = sm.tr.Lt[ty * 2 + 1][mm];
                        acc[0][0] += l0 * p0; acc[0][1] += l0 * p1;
                        acc[0][2] += l0 * p2; acc[0][3] += l0 * p3;
                        acc[1][0] += l1 * p0; acc[1][1] += l1 * p1;
                        acc[1][2] += l1 * p2; acc[1][3] += l1 * p3;
                    }
#pragma unroll
                    for (int rr = 0; rr < 2; rr++)
#pragma unroll
                        for (int cc = 0; cc < 4; cc++)
                            G[(size_t)(rb + ty * 2 + rr) * 1024 + cbase + tx * 4 + cc] -=
                                acc[rr][cc];
                }
            }
        }
        gg.sync();
    }

    // ---- phase 4: convert K (right half of G) to bf16 ----
    {
        int e = gtid * 4;  // 65536 threads x 4 elems = 512*512
        int j = e >> 9, i = e & 511;
        const float* src = G + (size_t)j * 1024 + 512 + i;
        unsigned short* dst = Kb + j * 512 + i;
        float v0 = src[0], v1 = src[1], v2 = src[2], v3 = src[3];
        uint2 pk;
        pk.x = f2bf(v0) | ((unsigned)f2bf(v1) << 16);
        pk.y = f2bf(v2) | ((unsigned)f2bf(v3) << 16);
        *(uint2*)dst = pk;
    }
}

// ===========================================================================
// Legacy (fallback) Cayley kernels — used only if cooperative launch fails.
// ===========================================================================
__global__ void buildG_kernel(const float* __restrict__ W, float* __restrict__ G) {
    int r = blockIdx.x;
    for (int c = threadIdx.x; c < 1024; c += 256) {
        float v;
        if (c < 512) {
            float a = W[r * 512 + c] - W[c * 512 + r];
            v = (c == r ? 1.f : 0.f) + a;
        } else {
            int c2 = c - 512;
            float a = W[r * 512 + c2] - W[c2 * 512 + r];
            v = (c2 == r ? 1.f : 0.f) - a;
        }
        G[(size_t)r * 1024 + c] = v;
    }
}

__global__ __launch_bounds__(512) void invdiag_kernel(float* __restrict__ G,
                                                      float* __restrict__ Dinv, int k) {
    int ck = k * 128;
    __shared__ float prow[2][256];
    __shared__ float pcol[2][128];
    int t = threadIdx.x;
    int c0 = t & 63, rg = t >> 6;
    float rgs[16][4];
#pragma unroll
    for (int m = 0; m < 16; m++) {
        int r = rg + 8 * m;
#pragma unroll
        for (int q = 0; q < 4; q++) {
            int c = c0 + 64 * q;
            rgs[m][q] = (c < 128) ? G[(size_t)(ck + r) * 1024 + ck + c]
                                  : ((r == c - 128) ? 1.f : 0.f);
        }
    }
    if (rg == 0) {
#pragma unroll
        for (int q = 0; q < 4; q++) prow[0][c0 + 64 * q] = rgs[0][q];
    }
    if (c0 == 0) {
#pragma unroll
        for (int m = 0; m < 16; m++) pcol[0][rg + 8 * m] = rgs[m][0];
    }
    __syncthreads();
    for (int p = 0; p < 128; p++) {
        int buf = p & 1;
        float inv = 1.0f / prow[buf][p];
        float pr[4];
#pragma unroll
        for (int q = 0; q < 4; q++) pr[q] = prow[buf][c0 + 64 * q];
#pragma unroll
        for (int m = 0; m < 16; m++) {
            int r = rg + 8 * m;
            if (r == p) {
#pragma unroll
                for (int q = 0; q < 4; q++) rgs[m][q] = pr[q] * inv;
            } else {
                float f = pcol[buf][r] * inv;
#pragma unroll
                for (int q = 0; q < 4; q++) rgs[m][q] -= f * pr[q];
            }
        }
        if (p < 127) {
            int p2 = p + 1, nb = p2 & 1;
            int mp = p2 >> 3, qp = p2 >> 6;
            if (rg == (p2 & 7)) {
#pragma unroll
                for (int m = 0; m < 16; m++)
                    if (m == mp) {
#pragma unroll
                        for (int q = 0; q < 4; q++) prow[nb][c0 + 64 * q] = rgs[m][q];
                    }
            }
            if (c0 == (p2 & 63)) {
#pragma unroll
                for (int q = 0; q < 4; q++)
                    if (q == qp) {
#pragma unroll
                        for (int m = 0; m < 16; m++) pcol[nb][rg + 8 * m] = rgs[m][q];
                    }
            }
        }
        __syncthreads();
    }
#pragma unroll
    for (int m = 0; m < 16; m++) {
        Dinv[(rg + 8 * m) * 128 + c0] = rgs[m][2];
        Dinv[(rg + 8 * m) * 128 + c0 + 64] = rgs[m][3];
    }
}

__global__ void rowscale_kernel(float* __restrict__ G, const float* __restrict__ Dinv,
                                int k) {
    int ck = k * 128;
    int cbase = ck + 128 + blockIdx.x * 64;
    __shared__ float ins[128][64];
    __shared__ float dch[128][33];
    int t = threadIdx.x;
    for (int idx = t; idx < 128 * 64; idx += 256) {
        int r = idx >> 6, c = idx & 63;
        ins[r][c] = G[(size_t)(ck + r) * 1024 + cbase + c];
    }
    int tx = t & 15, ty = t >> 4;
    float acc[8][4];
#pragma unroll
    for (int i = 0; i < 8; i++)
#pragma unroll
        for (int j = 0; j < 4; j++) acc[i][j] = 0.f;
    for (int mc = 0; mc < 4; mc++) {
        __syncthreads();
        for (int idx = t; idx < 128 * 32; idx += 256) {
            int r = idx >> 5, c = idx & 31;
            dch[r][c] = Dinv[r * 128 + mc * 32 + c];
        }
        __syncthreads();
        for (int m2 = 0; m2 < 32; m2++) {
            int mm = mc * 32 + m2;
            float p0 = ins[mm][tx * 4 + 0], p1 = ins[mm][tx * 4 + 1];
            float p2 = ins[mm][tx * 4 + 2], p3 = ins[mm][tx * 4 + 3];
#pragma unroll
            for (int rr = 0; rr < 8; rr++) {
                float d = dch[ty * 8 + rr][m2];
                acc[rr][0] += d * p0;
                acc[rr][1] += d * p1;
                acc[rr][2] += d * p2;
                acc[rr][3] += d * p3;
            }
        }
    }
#pragma unroll
    for (int rr = 0; rr < 8; rr++)
#pragma unroll
        for (int cc = 0; cc < 4; cc++)
            G[(size_t)(ck + ty * 8 + rr) * 1024 + cbase + tx * 4 + cc] = acc[rr][cc];
}

__global__ void trailing_kernel(float* __restrict__ G, int k) {
    int ck = k * 128;
    int rb = blockIdx.x * 32;
    if (rb >= ck) rb += 128;
    int cbase = ck + 128 + blockIdx.y * 64;
    __shared__ float Lt[32][129];
    __shared__ float Pt[128][64];
    int t = threadIdx.x;
    for (int idx = t; idx < 32 * 128; idx += 256) {
        int r = idx >> 7, c = idx & 127;
        Lt[r][c] = G[(size_t)(rb + r) * 1024 + ck + c];
    }
    for (int idx = t; idx < 128 * 64; idx += 256) {
        int r = idx >> 6, c = idx & 63;
        Pt[r][c] = G[(size_t)(ck + r) * 1024 + cbase + c];
    }
    __syncthreads();
    int tx = t & 15, ty = t >> 4;
    float acc[2][4];
#pragma unroll
    for (int i = 0; i < 2; i++)
#pragma unroll
        for (int j = 0; j < 4; j++) acc[i][j] = 0.f;
    for (int mm = 0; mm < 128; mm++) {
        float p0 = Pt[mm][tx * 4 + 0], p1 = Pt[mm][tx * 4 + 1];
        float p2 = Pt[mm][tx * 4 + 2], p3 = Pt[mm][tx * 4 + 3];
        float l0 = Lt[ty * 2 + 0][mm], l1 = Lt[ty * 2 + 1][mm];
        acc[0][0] += l0 * p0; acc[0][1] += l0 * p1; acc[0][2] += l0 * p2; acc[0][3] += l0 * p3;
        acc[1][0] += l1 * p0; acc[1][1] += l1 * p1; acc[1][2] += l1 * p2; acc[1][3] += l1 * p3;
    }
#pragma unroll
    for (int rr = 0; rr < 2; rr++)
#pragma unroll
        for (int cc = 0; cc < 4; cc++)
            G[(size_t)(rb + ty * 2 + rr) * 1024 + cbase + tx * 4 + cc] -= acc[rr][cc];
}

__global__ void cvtK_kernel(const float* __restrict__ G, unsigned short* __restrict__ Kb) {
    int idx = blockIdx.x * 256 + threadIdx.x;
    int e = idx * 4;
    int j = e >> 9, i = e & 511;
    const float* src = G + (size_t)j * 1024 + 512 + i;
    unsigned short* dst = Kb + j * 512 + i;
    float v0 = src[0], v1 = src[1], v2 = src[2], v3 = src[3];
    uint2 pk;
    pk.x = f2bf(v0) | ((unsigned)f2bf(v1) << 16);
    pk.y = f2bf(v2) | ((unsigned)f2bf(v3) << 16);
    *(uint2*)dst = pk;
}

// ===========================================================================
// Main GEMM: y[b, j, n] = sum_i K[j,i] x[b,i,n].  Block = all 512 j, 64 n.
// 512 threads = 8 waves; wave w owns j in [64w, 64w+64), mfma 16x16x32 bf16.
// v3: nontemporal loads of x, nontemporal stores of y (each element touched
// exactly once -> keep 1 GB/iter of streaming data out of the LLC so the
// small-kernel phase isn't crushed by dirty-line evictions).
// ===========================================================================
#define LDX 40  // padded xt row length (bf16 elems)

__global__ __launch_bounds__(512, 2) void gemm_kernel(const float* __restrict__ x,
                                                      const unsigned short* __restrict__ Kb,
                                                      float* __restrict__ y) {
    __shared__ unsigned short kt[2][512 * 32];  // K tiles: 512 j x 32 i (bf16), linear
    __shared__ unsigned short xt[2][64 * LDX];  // x tiles: 64 n x 32 i (bf16), padded
    int t = threadIdx.x;
    int l = t & 63, w = t >> 6;
    int bx = blockIdx.x;
    int b = bx >> 8;
    int n0 = (bx & 255) << 6;
    const float* xb = x + (size_t)b * CDIM * NSEQ + n0;
    float* yb = y + (size_t)b * CDIM * NSEQ + n0;

    int lr = l & 15;
    int q8 = (l >> 4) * 8;            // k-offset (bf16 elems) of this lane's fragment
    int kidx = q8 ^ ((lr & 3) << 3);  // swizzled k-offset for kt reads

    // per-lane swizzled global source for K staging
    const char* kgl = (const char*)Kb + (size_t)(64 * w + (l >> 2)) * 1024 +
                      (((l & 3) * 16) ^ (((l >> 2) & 3) << 4));

    f32x4 acc[4][4];
#pragma unroll
    for (int i = 0; i < 4; i++)
#pragma unroll
        for (int j = 0; j < 4; j++) acc[i][j] = (f32x4){0.f, 0.f, 0.f, 0.f};

    // ---- prologue: stage s=0 into buffer 0 ----
    {
        unsigned short* kdst = kt[0] + w * 64 * 32;
#pragma unroll
        for (int i = 0; i < 4; i++) gll16(kgl + i * 16384, kdst + i * 16 * 32);
        const float* xs = xb + (size_t)(w * 4) * NSEQ + l;
        uint2 pk;
        pk.x = f2bf(__builtin_nontemporal_load(xs)) |
               ((unsigned)f2bf(__builtin_nontemporal_load(xs + NSEQ)) << 16);
        pk.y = f2bf(__builtin_nontemporal_load(xs + 2 * NSEQ)) |
               ((unsigned)f2bf(__builtin_nontemporal_load(xs + 3 * NSEQ)) << 16);
        *(uint2*)(xt[0] + l * LDX + w * 4) = pk;
    }

    for (int s = 0; s < 16; s++) {
        const unsigned short* ktc = kt[s & 1];
        const unsigned short* xtc = xt[s & 1];
        __syncthreads();  // buf[s&1] fully staged

        // ---- prefetch s+1 (issue early; latency hides under MFMAs) ----
        float v0, v1, v2, v3;
        if (s < 15) {
            unsigned short* kdst = kt[(s + 1) & 1] + w * 64 * 32;
#pragma unroll
            for (int i = 0; i < 4; i++)
                gll16(kgl + (size_t)(s + 1) * 64 + i * 16384, kdst + i * 16 * 32);
            const float* xs = xb + (size_t)((s + 1) * 32 + w * 4) * NSEQ + l;
            v0 = __builtin_nontemporal_load(xs);
            v1 = __builtin_nontemporal_load(xs + NSEQ);
            v2 = __builtin_nontemporal_load(xs + 2 * NSEQ);
            v3 = __builtin_nontemporal_load(xs + 3 * NSEQ);
        }

        // ---- compute on buf[s&1] ----
        short8 af[4], bfr[4];
#pragma unroll
        for (int mt = 0; mt < 4; mt++)
            af[mt] = *(const short8*)(ktc + (w * 64 + mt * 16 + lr) * 32 + kidx);
#pragma unroll
        for (int nt = 0; nt < 4; nt++)
            bfr[nt] = *(const short8*)(xtc + (nt * 16 + lr) * LDX + q8);
#pragma unroll
        for (int mt = 0; mt < 4; mt++)
#pragma unroll
            for (int nt = 0; nt < 4; nt++)
                acc[mt][nt] = __builtin_amdgcn_mfma_f32_16x16x32_bf16(af[mt], bfr[nt],
                                                                      acc[mt][nt], 0, 0, 0);

        // ---- late write of prefetched x into the next buffer ----
        if (s < 15) {
            uint2 pk;
            pk.x = f2bf(v0) | ((unsigned)f2bf(v1) << 16);
            pk.y = f2bf(v2) | ((unsigned)f2bf(v3) << 16);
            *(uint2*)(xt[(s + 1) & 1] + l * LDX + w * 4) = pk;
        }
    }

    int qr = (l >> 4) * 4;
#pragma unroll
    for (int mt = 0; mt < 4; mt++)
#pragma unroll
        for (int nt = 0; nt < 4; nt++)
#pragma unroll
            for (int r = 0; r < 4; r++)
                __builtin_nontemporal_store(
                    acc[mt][nt][r],
                    &yb[(size_t)(w * 64 + mt * 16 + qr + r) * NSEQ + nt * 16 + lr]);
}

// ---------------------------------------------------------------------------
extern "C" void kernel_launch(void* const* d_in, const int* in_sizes, int n_in,
                              void* d_out, int out_size, void* d_ws, size_t ws_size,
                              hipStream_t stream) {
    const float* x = (const float*)d_in[0];
    const float* W = (const float*)d_in[1];
    float* y = (float*)d_out;

    float* G = (float*)d_ws;                                         // 2 MB
    float* DINV = (float*)((char*)d_ws + 0x200000);                  // 64 KB
    float* PB = (float*)((char*)d_ws + 0x210000);                    // 448 KB
    unsigned short* KB = (unsigned short*)((char*)d_ws + 0x280000);  // 512 KB

    const float* Wp = W;
    float* Gp = G;
    float* Dp = DINV;
    float* Pp = PB;
    unsigned short* Kp = KB;
    void* args[] = {(void*)&Wp, (void*)&Gp, (void*)&Dp, (void*)&Pp, (void*)&Kp};
    hipError_t ce = hipLaunchCooperativeKernel((void*)cayley_kernel, dim3(128), dim3(512),
                                               args, 0, stream);
    if (ce != hipSuccess) {
        // fallback: legacy multi-kernel path
        buildG_kernel<<<512, 256, 0, stream>>>(W, G);
        for (int k = 0; k < 4; k++) {
            invdiag_kernel<<<1, 512, 0, stream>>>(G, DINV, k);
            int ncols = 896 - 128 * k;
            rowscale_kernel<<<ncols / 64, 256, 0, stream>>>(G, DINV, k);
            trailing_kernel<<<dim3(12, ncols / 64), 256, 0, stream>>>(G, k);
        }
        cvtK_kernel<<<256, 256, 0, stream>>>(G, KB);
    }
    gemm_kernel<<<4096, 512, 0, stream>>>(x, KB, y);
}

// Round 3
// 1957.017 us; speedup vs baseline: 1.4218x; 1.0209x over previous
//
#include <hip/hip_runtime.h>

typedef __attribute__((ext_vector_type(8))) short short8;
typedef __attribute__((ext_vector_type(4))) float f32x4;

#define CDIM 512
#define NSEQ 16384

__device__ __forceinline__ unsigned short f2bf(float f) {
    unsigned u = __float_as_uint(f);
    unsigned r = ((u >> 16) & 1u) + 0x7fffu;
    return (unsigned short)((u + r) >> 16);
}

__device__ __forceinline__ void gll16(const void* g, void* l) {
    __builtin_amdgcn_global_load_lds((const __attribute__((address_space(1))) unsigned int*)g,
                                     (__attribute__((address_space(3))) unsigned int*)l,
                                     16, 0, 0);
}

// Custom grid barrier among the first NBLK blocks (device-scope atomics,
// sense-reversing via generation counter).  Requires co-residency
// (guaranteed by hipLaunchCooperativeKernel).
__device__ __forceinline__ void gbarrier(unsigned* cnt, unsigned* gen, unsigned nblk) {
    __syncthreads();
    if (threadIdx.x == 0) {
        unsigned g = __hip_atomic_load(gen, __ATOMIC_RELAXED, __HIP_MEMORY_SCOPE_AGENT);
        unsigned a =
            __hip_atomic_fetch_add(cnt, 1u, __ATOMIC_ACQ_REL, __HIP_MEMORY_SCOPE_AGENT);
        if (a == nblk - 1u) {
            __hip_atomic_store(cnt, 0u, __ATOMIC_RELAXED, __HIP_MEMORY_SCOPE_AGENT);
            __hip_atomic_fetch_add(gen, 1u, __ATOMIC_RELEASE, __HIP_MEMORY_SCOPE_AGENT);
        } else {
            while (__hip_atomic_load(gen, __ATOMIC_ACQUIRE, __HIP_MEMORY_SCOPE_AGENT) == g)
                __builtin_amdgcn_s_sleep(2);
        }
    }
    __syncthreads();
}

// ===========================================================================
// Fused pre-pass (cooperative, 256 blocks x 512 threads):
//   blocks 0..63  : Cayley factorization (buildG -> 4x(inv,rowscale,trailing)
//                   -> cvtK), synced by the custom 64-block barrier.
//   blocks 64..255: convert+transpose x (f32 [b][i][n]) -> xT (bf16 [b][n][i]),
//                   running straight through (no barrier participation).
// Keeps all 256 CUs busy during the factorization's serial sections.
// ===========================================================================
__global__ __launch_bounds__(512, 1) void fused_pre_kernel(
    const float* __restrict__ x, const float* __restrict__ W, float* __restrict__ G,
    float* __restrict__ Dinv, float* __restrict__ Pbuf, unsigned short* __restrict__ Kb,
    unsigned short* __restrict__ xT, unsigned* __restrict__ bar) {
    __shared__ union {
        struct { float prow[2][256]; float pcol[2][128]; } inv;
        struct { float ins[128][64]; float dch[128][33]; } rs;
        struct { float Lt[64][129]; float Pt[128][64]; } tr;
        struct { float tile[64][129]; } cv;
    } sm;

    int t = threadIdx.x;
    int bid = blockIdx.x;

    if (bid >= 64) {
        // ---------------- converter role: x -> xT (bf16, transposed) -------
        for (int tile = bid - 64; tile < 16384; tile += 192) {
            int b = tile >> 10, rem = tile & 1023;
            int i0 = (rem >> 7) << 6, n0 = (rem & 127) << 7;  // 64 i x 128 n
            __syncthreads();
            for (int k2 = t; k2 < 64 * 128; k2 += 512) {
                int i = k2 >> 7, n = k2 & 127;
                sm.cv.tile[i][n] = x[((size_t)b * 512 + i0 + i) * NSEQ + n0 + n];
            }
            __syncthreads();
#pragma unroll
            for (int r = 0; r < 2; r++) {
                int task = t + (r << 9);
                int n = task >> 3, oc = task & 7;
                float v0 = sm.cv.tile[oc * 8 + 0][n], v1 = sm.cv.tile[oc * 8 + 1][n];
                float v2 = sm.cv.tile[oc * 8 + 2][n], v3 = sm.cv.tile[oc * 8 + 3][n];
                float v4 = sm.cv.tile[oc * 8 + 4][n], v5 = sm.cv.tile[oc * 8 + 5][n];
                float v6 = sm.cv.tile[oc * 8 + 6][n], v7 = sm.cv.tile[oc * 8 + 7][n];
                uint4 pk;
                pk.x = f2bf(v0) | ((unsigned)f2bf(v1) << 16);
                pk.y = f2bf(v2) | ((unsigned)f2bf(v3) << 16);
                pk.z = f2bf(v4) | ((unsigned)f2bf(v5) << 16);
                pk.w = f2bf(v6) | ((unsigned)f2bf(v7) << 16);
                *(uint4*)(xT + ((size_t)b * NSEQ + n0 + n) * 512 + i0 + oc * 8) = pk;
            }
        }
        return;
    }

    // ---------------- factorization role (blocks 0..63) -------------------
    unsigned* cnt = bar;
    unsigned* gen = bar + 1;

    // phase 0: G = [I + A | I - A], A = W - W^T
    for (int e = bid * 512 + t; e < 512 * 1024; e += 64 * 512) {
        int r = e >> 10, c = e & 1023;
        float v;
        if (c < 512) {
            float a = W[r * 512 + c] - W[c * 512 + r];
            v = (c == r ? 1.f : 0.f) + a;
        } else {
            int c2 = c - 512;
            float a = W[r * 512 + c2] - W[c2 * 512 + r];
            v = (c2 == r ? 1.f : 0.f) - a;
        }
        G[e] = v;
    }
    gbarrier(cnt, gen, 64);

    for (int k = 0; k < 4; k++) {
        int ck = k * 128;
        int nct = (896 - 128 * k) >> 6;

        // phase 1: invert 128x128 diagonal block (block 0, register GJ)
        if (bid == 0) {
            int c0 = t & 63, rg = t >> 6;
            float rgs[16][4];
#pragma unroll
            for (int m = 0; m < 16; m++) {
                int r = rg + 8 * m;
#pragma unroll
                for (int q = 0; q < 4; q++) {
                    int c = c0 + 64 * q;
                    rgs[m][q] = (c < 128) ? G[(size_t)(ck + r) * 1024 + ck + c]
                                          : ((r == c - 128) ? 1.f : 0.f);
                }
            }
            if (rg == 0) {
#pragma unroll
                for (int q = 0; q < 4; q++) sm.inv.prow[0][c0 + 64 * q] = rgs[0][q];
            }
            if (c0 == 0) {
#pragma unroll
                for (int m = 0; m < 16; m++) sm.inv.pcol[0][rg + 8 * m] = rgs[m][0];
            }
            __syncthreads();
            for (int p = 0; p < 128; p++) {
                int buf = p & 1;
                float inv = 1.0f / sm.inv.prow[buf][p];
                float pr[4];
#pragma unroll
                for (int q = 0; q < 4; q++) pr[q] = sm.inv.prow[buf][c0 + 64 * q];
#pragma unroll
                for (int m = 0; m < 16; m++) {
                    int r = rg + 8 * m;
                    if (r == p) {
#pragma unroll
                        for (int q = 0; q < 4; q++) rgs[m][q] = pr[q] * inv;
                    } else {
                        float f = sm.inv.pcol[buf][r] * inv;
#pragma unroll
                        for (int q = 0; q < 4; q++) rgs[m][q] -= f * pr[q];
                    }
                }
                if (p < 127) {
                    int p2 = p + 1, nb = p2 & 1;
                    int mp = p2 >> 3, qp = p2 >> 6;
                    if (rg == (p2 & 7)) {
#pragma unroll
                        for (int m = 0; m < 16; m++)
                            if (m == mp) {
#pragma unroll
                                for (int q = 0; q < 4; q++)
                                    sm.inv.prow[nb][c0 + 64 * q] = rgs[m][q];
                            }
                    }
                    if (c0 == (p2 & 63)) {
#pragma unroll
                        for (int q = 0; q < 4; q++)
                            if (q == qp) {
#pragma unroll
                                for (int m = 0; m < 16; m++)
                                    sm.inv.pcol[nb][rg + 8 * m] = rgs[m][q];
                            }
                    }
                }
                __syncthreads();
            }
#pragma unroll
            for (int m = 0; m < 16; m++) {
                Dinv[(rg + 8 * m) * 128 + c0] = rgs[m][2];
                Dinv[(rg + 8 * m) * 128 + c0 + 64] = rgs[m][3];
            }
        }
        gbarrier(cnt, gen, 64);

        // phase 2: P = Dinv x G[Rk, active] -> Pbuf[128][896]
        if (bid < nct) {
            int cbase = ck + 128 + bid * 64;
            for (int idx = t; idx < 128 * 64; idx += 512) {
                int r = idx >> 6, c = idx & 63;
                sm.rs.ins[r][c] = G[(size_t)(ck + r) * 1024 + cbase + c];
            }
            int tx = t & 15, ty = t >> 4;
            float acc[4][4];
#pragma unroll
            for (int i = 0; i < 4; i++)
#pragma unroll
                for (int j = 0; j < 4; j++) acc[i][j] = 0.f;
            for (int mc = 0; mc < 4; mc++) {
                __syncthreads();
                for (int idx = t; idx < 128 * 32; idx += 512) {
                    int r = idx >> 5, c = idx & 31;
                    sm.rs.dch[r][c] = Dinv[r * 128 + mc * 32 + c];
                }
                __syncthreads();
                for (int m2 = 0; m2 < 32; m2++) {
                    int mm = mc * 32 + m2;
                    float p0 = sm.rs.ins[mm][tx * 4 + 0], p1 = sm.rs.ins[mm][tx * 4 + 1];
                    float p2 = sm.rs.ins[mm][tx * 4 + 2], p3 = sm.rs.ins[mm][tx * 4 + 3];
#pragma unroll
                    for (int rr = 0; rr < 4; rr++) {
                        float d = sm.rs.dch[ty * 4 + rr][m2];
                        acc[rr][0] += d * p0;
                        acc[rr][1] += d * p1;
                        acc[rr][2] += d * p2;
                        acc[rr][3] += d * p3;
                    }
                }
            }
#pragma unroll
            for (int rr = 0; rr < 4; rr++)
#pragma unroll
                for (int cc = 0; cc < 4; cc++)
                    Pbuf[(ty * 4 + rr) * 896 + bid * 64 + tx * 4 + cc] = acc[rr][cc];
        }
        gbarrier(cnt, gen, 64);

        // phase 3: trailing update + pivot-row copy (loop tiles over 64 blocks)
        for (int tl = bid; tl < nct * 8; tl += 64) {
            int ct = tl >> 3, rt = tl & 7;
            int cbase = ck + 128 + ct * 64;
            int rb = rt * 64;
            bool pivot = (rb >= ck) && (rb < ck + 128);
            __syncthreads();
            if (pivot) {
                for (int idx = t; idx < 64 * 64; idx += 512) {
                    int r = idx >> 6, c = idx & 63;
                    G[(size_t)(rb + r) * 1024 + cbase + c] =
                        Pbuf[(rb - ck + r) * 896 + ct * 64 + c];
                }
            } else {
                for (int idx = t; idx < 64 * 128; idx += 512) {
                    int r = idx >> 7, c = idx & 127;
                    sm.tr.Lt[r][c] = G[(size_t)(rb + r) * 1024 + ck + c];
                }
                for (int idx = t; idx < 128 * 64; idx += 512) {
                    int r = idx >> 6, c = idx & 63;
                    sm.tr.Pt[r][c] = Pbuf[r * 896 + ct * 64 + c];
                }
                __syncthreads();
                int tx = t & 15, ty = t >> 4;
                float acc[2][4];
#pragma unroll
                for (int i = 0; i < 2; i++)
#pragma unroll
                    for (int j = 0; j < 4; j++) acc[i][j] = 0.f;
                for (int mm = 0; mm < 128; mm++) {
                    float p0 = sm.tr.Pt[mm][tx * 4 + 0], p1 = sm.tr.Pt[mm][tx * 4 + 1];
                    float p2 = sm.tr.Pt[mm][tx * 4 + 2], p3 = sm.tr.Pt[mm][tx * 4 + 3];
                    float l0 = sm.tr.Lt[ty * 2 + 0][mm], l1 = sm.tr.Lt[ty * 2 + 1][mm];
                    acc[0][0] += l0 * p0; acc[0][1] += l0 * p1;
                    acc[0][2] += l0 * p2; acc[0][3] += l0 * p3;
                    acc[1][0] += l1 * p0; acc[1][1] += l1 * p1;
                    acc[1][2] += l1 * p2; acc[1][3] += l1 * p3;
                }
#pragma unroll
                for (int rr = 0; rr < 2; rr++)
#pragma unroll
                    for (int cc = 0; cc < 4; cc++)
                        G[(size_t)(rb + ty * 2 + rr) * 1024 + cbase + tx * 4 + cc] -=
                            acc[rr][cc];
            }
        }
        gbarrier(cnt, gen, 64);
    }

    // phase 4: K (right half of G) -> bf16
    for (int g2 = bid * 512 + t; g2 < 65536; g2 += 64 * 512) {
        int e = g2 * 4;
        int j = e >> 9, i = e & 511;
        const float* src = G + (size_t)j * 1024 + 512 + i;
        float v0 = src[0], v1 = src[1], v2 = src[2], v3 = src[3];
        uint2 pk;
        pk.x = f2bf(v0) | ((unsigned)f2bf(v1) << 16);
        pk.y = f2bf(v2) | ((unsigned)f2bf(v3) << 16);
        *(uint2*)(Kb + j * 512 + i) = pk;
    }
}

// ===========================================================================
// Main GEMM v4: y[b,j,n] = sum_i K[j,i] xT[b,n,i].  Both operands bf16 in
// global; both staged with global_load_lds (quarter-swizzled); plain cached
// stores (NT removed — it defeated L2 write-combining, ~2x store cost).
// ===========================================================================
__global__ __launch_bounds__(512, 2) void gemm_bf16_kernel(
    const unsigned short* __restrict__ xT, const unsigned short* __restrict__ Kb,
    float* __restrict__ y) {
    __shared__ unsigned short kt[2][512 * 32];  // 512 j x 32 i, 64B rows, swizzled
    __shared__ unsigned short xt[2][64 * 32];   // 64 n x 32 i, 64B rows, swizzled
    int t = threadIdx.x;
    int l = t & 63, w = t >> 6;
    int bx = blockIdx.x;
    int b = bx >> 8;
    int n0 = (bx & 255) << 6;
    float* yb = y + (size_t)b * CDIM * NSEQ + n0;

    int lr = l & 15;
    int g = l >> 4;
    int q8 = g * 8;
    int kidx = q8 ^ ((lr & 3) << 3);        // kt slot offset (shorts)
    int xidx = q8 ^ (((lr >> 1) & 3) << 3); // xt slot offset (shorts)

    // K staging: wave w rows j=64w+.., quarter-swizzled source
    const char* kgl = (const char*)Kb + (size_t)(64 * w + (l >> 2)) * 1024 +
                      (((l & 3) * 16) ^ (((l >> 2) & 3) << 4));
    // x staging (waves 0..3): row n0+16w+(l>>2), quarter (l&3)^((l>>3)&3)
    const char* xgl =
        (const char*)xT + ((size_t)((size_t)b * NSEQ + n0 + 16 * w + (l >> 2)) * 512 +
                           (((l & 3) ^ ((l >> 3) & 3)) * 8)) *
                              2;

    f32x4 acc[4][4];
#pragma unroll
    for (int i = 0; i < 4; i++)
#pragma unroll
        for (int j = 0; j < 4; j++) acc[i][j] = (f32x4){0.f, 0.f, 0.f, 0.f};

    // prologue: stage s=0
    {
        unsigned short* kdst = kt[0] + w * 2048;
#pragma unroll
        for (int i = 0; i < 4; i++) gll16(kgl + i * 16384, kdst + i * 512);
        if (w < 4) gll16(xgl, xt[0] + w * 512);
    }

    for (int s = 0; s < 16; s++) {
        const unsigned short* ktc = kt[s & 1];
        const unsigned short* xtc = xt[s & 1];
        __syncthreads();  // buf[s&1] staged

        if (s < 15) {  // stage s+1 early; latency hides under MFMAs
            unsigned short* kdst = kt[(s + 1) & 1] + w * 2048;
#pragma unroll
            for (int i = 0; i < 4; i++)
                gll16(kgl + (s + 1) * 64 + i * 16384, kdst + i * 512);
            if (w < 4) gll16(xgl + (s + 1) * 64, xt[(s + 1) & 1] + w * 512);
        }

        short8 af[4], bfr[4];
#pragma unroll
        for (int mt = 0; mt < 4; mt++)
            af[mt] = *(const short8*)(ktc + (w * 64 + mt * 16 + lr) * 32 + kidx);
#pragma unroll
        for (int nt = 0; nt < 4; nt++)
            bfr[nt] = *(const short8*)(xtc + (nt * 16 + lr) * 32 + xidx);
#pragma unroll
        for (int mt = 0; mt < 4; mt++)
#pragma unroll
            for (int nt = 0; nt < 4; nt++)
                acc[mt][nt] = __builtin_amdgcn_mfma_f32_16x16x32_bf16(af[mt], bfr[nt],
                                                                      acc[mt][nt], 0, 0, 0);
    }

    int qr = g * 4;
#pragma unroll
    for (int mt = 0; mt < 4; mt++)
#pragma unroll
        for (int nt = 0; nt < 4; nt++)
#pragma unroll
            for (int r = 0; r < 4; r++)
                yb[(size_t)(w * 64 + mt * 16 + qr + r) * NSEQ + nt * 16 + lr] =
                    acc[mt][nt][r];
}

// ===========================================================================
// Legacy fallback path (non-cooperative), used if ws is too small or the
// cooperative launch fails.
// ===========================================================================
__global__ void buildG_kernel(const float* __restrict__ W, float* __restrict__ G) {
    int r = blockIdx.x;
    for (int c = threadIdx.x; c < 1024; c += 256) {
        float v;
        if (c < 512) {
            float a = W[r * 512 + c] - W[c * 512 + r];
            v = (c == r ? 1.f : 0.f) + a;
        } else {
            int c2 = c - 512;
            float a = W[r * 512 + c2] - W[c2 * 512 + r];
            v = (c2 == r ? 1.f : 0.f) - a;
        }
        G[(size_t)r * 1024 + c] = v;
    }
}

__global__ __launch_bounds__(512) void invdiag_kernel(float* __restrict__ G,
                                                      float* __restrict__ Dinv, int k) {
    int ck = k * 128;
    __shared__ float prow[2][256];
    __shared__ float pcol[2][128];
    int t = threadIdx.x;
    int c0 = t & 63, rg = t >> 6;
    float rgs[16][4];
#pragma unroll
    for (int m = 0; m < 16; m++) {
        int r = rg + 8 * m;
#pragma unroll
        for (int q = 0; q < 4; q++) {
            int c = c0 + 64 * q;
            rgs[m][q] = (c < 128) ? G[(size_t)(ck + r) * 1024 + ck + c]
                                  : ((r == c - 128) ? 1.f : 0.f);
        }
    }
    if (rg == 0) {
#pragma unroll
        for (int q = 0; q < 4; q++) prow[0][c0 + 64 * q] = rgs[0][q];
    }
    if (c0 == 0) {
#pragma unroll
        for (int m = 0; m < 16; m++) pcol[0][rg + 8 * m] = rgs[m][0];
    }
    __syncthreads();
    for (int p = 0; p < 128; p++) {
        int buf = p & 1;
        float inv = 1.0f / prow[buf][p];
        float pr[4];
#pragma unroll
        for (int q = 0; q < 4; q++) pr[q] = prow[buf][c0 + 64 * q];
#pragma unroll
        for (int m = 0; m < 16; m++) {
            int r = rg + 8 * m;
            if (r == p) {
#pragma unroll
                for (int q = 0; q < 4; q++) rgs[m][q] = pr[q] * inv;
            } else {
                float f = pcol[buf][r] * inv;
#pragma unroll
                for (int q = 0; q < 4; q++) rgs[m][q] -= f * pr[q];
            }
        }
        if (p < 127) {
            int p2 = p + 1, nb = p2 & 1;
            int mp = p2 >> 3, qp = p2 >> 6;
            if (rg == (p2 & 7)) {
#pragma unroll
                for (int m = 0; m < 16; m++)
                    if (m == mp) {
#pragma unroll
                        for (int q = 0; q < 4; q++) prow[nb][c0 + 64 * q] = rgs[m][q];
                    }
            }
            if (c0 == (p2 & 63)) {
#pragma unroll
                for (int q = 0; q < 4; q++)
                    if (q == qp) {
#pragma unroll
                        for (int m = 0; m < 16; m++) pcol[nb][rg + 8 * m] = rgs[m][q];
                    }
            }
        }
        __syncthreads();
    }
#pragma unroll
    for (int m = 0; m < 16; m++) {
        Dinv[(rg + 8 * m) * 128 + c0] = rgs[m][2];
        Dinv[(rg + 8 * m) * 128 + c0 + 64] = rgs[m][3];
    }
}

__global__ void rowscale_kernel(float* __restrict__ G, const float* __restrict__ Dinv,
                                int k) {
    int ck = k * 128;
    int cbase = ck + 128 + blockIdx.x * 64;
    __shared__ float ins[128][64];
    __shared__ float dch[128][33];
    int t = threadIdx.x;
    for (int idx = t; idx < 128 * 64; idx += 256) {
        int r = idx >> 6, c = idx & 63;
        ins[r][c] = G[(size_t)(ck + r) * 1024 + cbase + c];
    }
    int tx = t & 15, ty = t >> 4;
    float acc[8][4];
#pragma unroll
    for (int i = 0; i < 8; i++)
#pragma unroll
        for (int j = 0; j < 4; j++) acc[i][j] = 0.f;
    for (int mc = 0; mc < 4; mc++) {
        __syncthreads();
        for (int idx = t; idx < 128 * 32; idx += 256) {
            int r = idx >> 5, c = idx & 31;
            dch[r][c] = Dinv[r * 128 + mc * 32 + c];
        }
        __syncthreads();
        for (int m2 = 0; m2 < 32; m2++) {
            int mm = mc * 32 + m2;
            float p0 = ins[mm][tx * 4 + 0], p1 = ins[mm][tx * 4 + 1];
            float p2 = ins[mm][tx * 4 + 2], p3 = ins[mm][tx * 4 + 3];
#pragma unroll
            for (int rr = 0; rr < 8; rr++) {
                float d = dch[ty * 8 + rr][m2];
                acc[rr][0] += d * p0;
                acc[rr][1] += d * p1;
                acc[rr][2] += d * p2;
                acc[rr][3] += d * p3;
            }
        }
    }
#pragma unroll
    for (int rr = 0; rr < 8; rr++)
#pragma unroll
        for (int cc = 0; cc < 4; cc++)
            G[(size_t)(ck + ty * 8 + rr) * 1024 + cbase + tx * 4 + cc] = acc[rr][cc];
}

__global__ void trailing_kernel(float* __restrict__ G, int k) {
    int ck = k * 128;
    int rb = blockIdx.x * 32;
    if (rb >= ck) rb += 128;
    int cbase = ck + 128 + blockIdx.y * 64;
    __shared__ float Lt[32][129];
    __shared__ float Pt[128][64];
    int t = threadIdx.x;
    for (int idx = t; idx < 32 * 128; idx += 256) {
        int r = idx >> 7, c = idx & 127;
        Lt[r][c] = G[(size_t)(rb + r) * 1024 + ck + c];
    }
    for (int idx = t; idx < 128 * 64; idx += 256) {
        int r = idx >> 6, c = idx & 63;
        Pt[r][c] = G[(size_t)(ck + r) * 1024 + cbase + c];
    }
    __syncthreads();
    int tx = t & 15, ty = t >> 4;
    float acc[2][4];
#pragma unroll
    for (int i = 0; i < 2; i++)
#pragma unroll
        for (int j = 0; j < 4; j++) acc[i][j] = 0.f;
    for (int mm = 0; mm < 128; mm++) {
        float p0 = Pt[mm][tx * 4 + 0], p1 = Pt[mm][tx * 4 + 1];
        float p2 = Pt[mm][tx * 4 + 2], p3 = Pt[mm][tx * 4 + 3];
        float l0 = Lt[ty * 2 + 0][mm], l1 = Lt[ty * 2 + 1][mm];
        acc[0][0] += l0 * p0; acc[0][1] += l0 * p1; acc[0][2] += l0 * p2; acc[0][3] += l0 * p3;
        acc[1][0] += l1 * p0; acc[1][1] += l1 * p1; acc[1][2] += l1 * p2; acc[1][3] += l1 * p3;
    }
#pragma unroll
    for (int rr = 0; rr < 2; rr++)
#pragma unroll
        for (int cc = 0; cc < 4; cc++)
            G[(size_t)(rb + ty * 2 + rr) * 1024 + cbase + tx * 4 + cc] -= acc[rr][cc];
}

__global__ void cvtK_kernel(const float* __restrict__ G, unsigned short* __restrict__ Kb) {
    int idx = blockIdx.x * 256 + threadIdx.x;
    int e = idx * 4;
    int j = e >> 9, i = e & 511;
    const float* src = G + (size_t)j * 1024 + 512 + i;
    float v0 = src[0], v1 = src[1], v2 = src[2], v3 = src[3];
    uint2 pk;
    pk.x = f2bf(v0) | ((unsigned)f2bf(v1) << 16);
    pk.y = f2bf(v2) | ((unsigned)f2bf(v3) << 16);
    *(uint2*)(Kb + j * 512 + i) = pk;
}

#define LDX 40
__global__ __launch_bounds__(512, 2) void gemm_f32x_kernel(
    const float* __restrict__ x, const unsigned short* __restrict__ Kb,
    float* __restrict__ y) {
    __shared__ unsigned short kt[2][512 * 32];
    __shared__ unsigned short xt[2][64 * LDX];
    int t = threadIdx.x;
    int l = t & 63, w = t >> 6;
    int bx = blockIdx.x;
    int b = bx >> 8;
    int n0 = (bx & 255) << 6;
    const float* xb = x + (size_t)b * CDIM * NSEQ + n0;
    float* yb = y + (size_t)b * CDIM * NSEQ + n0;
    int lr = l & 15;
    int q8 = (l >> 4) * 8;
    int kidx = q8 ^ ((lr & 3) << 3);
    const char* kgl = (const char*)Kb + (size_t)(64 * w + (l >> 2)) * 1024 +
                      (((l & 3) * 16) ^ (((l >> 2) & 3) << 4));
    f32x4 acc[4][4];
#pragma unroll
    for (int i = 0; i < 4; i++)
#pragma unroll
        for (int j = 0; j < 4; j++) acc[i][j] = (f32x4){0.f, 0.f, 0.f, 0.f};
    {
        unsigned short* kdst = kt[0] + w * 2048;
#pragma unroll
        for (int i = 0; i < 4; i++) gll16(kgl + i * 16384, kdst + i * 512);
        const float* xs = xb + (size_t)(w * 4) * NSEQ + l;
        uint2 pk;
        pk.x = f2bf(xs[0]) | ((unsigned)f2bf(xs[NSEQ]) << 16);
        pk.y = f2bf(xs[2 * NSEQ]) | ((unsigned)f2bf(xs[3 * NSEQ]) << 16);
        *(uint2*)(xt[0] + l * LDX + w * 4) = pk;
    }
    for (int s = 0; s < 16; s++) {
        const unsigned short* ktc = kt[s & 1];
        const unsigned short* xtc = xt[s & 1];
        __syncthreads();
        float v0, v1, v2, v3;
        if (s < 15) {
            unsigned short* kdst = kt[(s + 1) & 1] + w * 2048;
#pragma unroll
            for (int i = 0; i < 4; i++)
                gll16(kgl + (s + 1) * 64 + i * 16384, kdst + i * 512);
            const float* xs = xb + (size_t)((s + 1) * 32 + w * 4) * NSEQ + l;
            v0 = xs[0]; v1 = xs[NSEQ]; v2 = xs[2 * NSEQ]; v3 = xs[3 * NSEQ];
        }
        short8 af[4], bfr[4];
#pragma unroll
        for (int mt = 0; mt < 4; mt++)
            af[mt] = *(const short8*)(ktc + (w * 64 + mt * 16 + lr) * 32 + kidx);
#pragma unroll
        for (int nt = 0; nt < 4; nt++)
            bfr[nt] = *(const short8*)(xtc + (nt * 16 + lr) * LDX + q8);
#pragma unroll
        for (int mt = 0; mt < 4; mt++)
#pragma unroll
            for (int nt = 0; nt < 4; nt++)
                acc[mt][nt] = __builtin_amdgcn_mfma_f32_16x16x32_bf16(af[mt], bfr[nt],
                                                                      acc[mt][nt], 0, 0, 0);
        if (s < 15) {
            uint2 pk;
            pk.x = f2bf(v0) | ((unsigned)f2bf(v1) << 16);
            pk.y = f2bf(v2) | ((unsigned)f2bf(v3) << 16);
            *(uint2*)(xt[(s + 1) & 1] + l * LDX + w * 4) = pk;
        }
    }
    int qr = (l >> 4) * 4;
#pragma unroll
    for (int mt = 0; mt < 4; mt++)
#pragma unroll
        for (int nt = 0; nt < 4; nt++)
#pragma unroll
            for (int r = 0; r < 4; r++)
                yb[(size_t)(w * 64 + mt * 16 + qr + r) * NSEQ + nt * 16 + lr] =
                    acc[mt][nt][r];
}

// ---------------------------------------------------------------------------
extern "C" void kernel_launch(void* const* d_in, const int* in_sizes, int n_in,
                              void* d_out, int out_size, void* d_ws, size_t ws_size,
                              hipStream_t stream) {
    const float* x = (const float*)d_in[0];
    const float* W = (const float*)d_in[1];
    float* y = (float*)d_out;

    float* G = (float*)d_ws;                                         // 2 MB
    float* DINV = (float*)((char*)d_ws + 0x200000);                  // 64 KB
    float* PB = (float*)((char*)d_ws + 0x210000);                    // 448 KB
    unsigned short* KB = (unsigned short*)((char*)d_ws + 0x280000);  // 512 KB
    unsigned* BAR = (unsigned*)((char*)d_ws + 0x300000);             // 64 B
    unsigned short* XT = (unsigned short*)((char*)d_ws + 0x400000);  // 256 MB

    const size_t need = 0x400000 + (size_t)16 * NSEQ * CDIM * 2;
    bool fused = ws_size >= need;

    if (fused) {
        hipMemsetAsync((char*)d_ws + 0x300000, 0, 64, stream);
        const float* xp = x;
        const float* Wp = W;
        float* Gp = G;
        float* Dp = DINV;
        float* Pp = PB;
        unsigned short* Kp = KB;
        unsigned short* Xp = XT;
        unsigned* Bp = BAR;
        void* args[] = {(void*)&xp, (void*)&Wp, (void*)&Gp, (void*)&Dp,
                        (void*)&Pp, (void*)&Kp, (void*)&Xp, (void*)&Bp};
        hipError_t ce = hipLaunchCooperativeKernel((void*)fused_pre_kernel, dim3(256),
                                                   dim3(512), args, 0, stream);
        if (ce != hipSuccess) fused = false;
    }

    if (!fused) {
        buildG_kernel<<<512, 256, 0, stream>>>(W, G);
        for (int k = 0; k < 4; k++) {
            invdiag_kernel<<<1, 512, 0, stream>>>(G, DINV, k);
            int ncols = 896 - 128 * k;
            rowscale_kernel<<<ncols / 64, 256, 0, stream>>>(G, DINV, k);
            trailing_kernel<<<dim3(12, ncols / 64), 256, 0, stream>>>(G, k);
        }
        cvtK_kernel<<<256, 256, 0, stream>>>(G, KB);
        gemm_f32x_kernel<<<4096, 512, 0, stream>>>(x, KB, y);
    } else {
        gemm_bf16_kernel<<<4096, 512, 0, stream>>>(XT, KB, y);
    }
}

// Round 4
// 1933.472 us; speedup vs baseline: 1.4391x; 1.0122x over previous
//
#include <hip/hip_runtime.h>

typedef __attribute__((ext_vector_type(8))) short short8;
typedef __attribute__((ext_vector_type(4))) float f32x4;

#define CDIM 512
#define NSEQ 16384

__device__ __forceinline__ unsigned short f2bf(float f) {
    unsigned u = __float_as_uint(f);
    unsigned r = ((u >> 16) & 1u) + 0x7fffu;
    return (unsigned short)((u + r) >> 16);
}

__device__ __forceinline__ void gll16(const void* g, void* l) {
    __builtin_amdgcn_global_load_lds((const __attribute__((address_space(1))) unsigned int*)g,
                                     (__attribute__((address_space(3))) unsigned int*)l,
                                     16, 0, 0);
}

// ---------------------------------------------------------------------------
// Grid barrier among the first NBLK blocks.  v2: RELAXED agent-scope polls
// (no per-poll L2 invalidate) + exactly one release/acquire __threadfence
// pair per crossing.  gen bump is RELEASE so the cnt reset can't reorder
// past it.
// ---------------------------------------------------------------------------
__device__ __forceinline__ void gbar(unsigned* cnt, unsigned* gen, unsigned nblk) {
    __syncthreads();
    if (threadIdx.x == 0) {
        __threadfence();  // release: make this block's writes agent-visible
        unsigned g = __hip_atomic_load(gen, __ATOMIC_RELAXED, __HIP_MEMORY_SCOPE_AGENT);
        unsigned a =
            __hip_atomic_fetch_add(cnt, 1u, __ATOMIC_RELAXED, __HIP_MEMORY_SCOPE_AGENT);
        if (a == nblk - 1u) {
            __hip_atomic_store(cnt, 0u, __ATOMIC_RELAXED, __HIP_MEMORY_SCOPE_AGENT);
            __hip_atomic_fetch_add(gen, 1u, __ATOMIC_RELEASE, __HIP_MEMORY_SCOPE_AGENT);
        } else {
            while (__hip_atomic_load(gen, __ATOMIC_RELAXED, __HIP_MEMORY_SCOPE_AGENT) == g)
                __builtin_amdgcn_s_sleep(8);
        }
        __threadfence();  // acquire: invalidate so we see peers' writes
    }
    __syncthreads();
}

// ===========================================================================
// Fused pre-pass (PLAIN launch, 256 blocks x 512 threads, 1 block/CU):
//   blocks 0..63  : Cayley factorization, proven round-3 phase logic,
//                   synced by the cheap-poll 64-block barrier.
//   blocks 64..255: FMA heater — keeps SCLK boosted during the serial GJ
//                   phases; exits on done-flag (relaxed poll), hard-capped
//                   so it always terminates (no deadlock possible).
// ===========================================================================
__global__ __launch_bounds__(512, 1) void fused_pre_kernel(
    const float* __restrict__ W, float* __restrict__ G, float* __restrict__ Dinv,
    float* __restrict__ Pbuf, unsigned short* __restrict__ Kb, unsigned* __restrict__ bar) {
    __shared__ union {
        struct { float prow[2][256]; float pcol[2][128]; } inv;
        struct { float ins[128][64]; float dch[128][33]; } rs;
        struct { float Lt[64][129]; float Pt[128][64]; } tr;
    } sm;

    int t = threadIdx.x;
    int bid = blockIdx.x;
    unsigned* cnt = bar;
    unsigned* gen = bar + 1;
    unsigned* flag = bar + 2;

    if (bid >= 64) {
        // ---------------- heater role ----------------
        float h0 = 1.0001f, h1 = 0.9999f, h2 = 1.0002f, h3 = 0.9998f;
        for (int it = 0; it < 4000; ++it) {
            if (__hip_atomic_load(flag, __ATOMIC_RELAXED, __HIP_MEMORY_SCOPE_AGENT)) break;
#pragma unroll
            for (int u = 0; u < 128; u++) {
                h0 = __builtin_fmaf(h0, h1, h2);
                h1 = __builtin_fmaf(h1, h2, h3);
                h2 = __builtin_fmaf(h2, h3, h0);
                h3 = __builtin_fmaf(h3, h0, h1);
            }
        }
        asm volatile("" ::"v"(h0), "v"(h1), "v"(h2), "v"(h3));
        return;
    }

    // ---------------- factorization role (blocks 0..63) -------------------
    // phase 0: G = [I + A | I - A], A = W - W^T
    for (int e = bid * 512 + t; e < 512 * 1024; e += 64 * 512) {
        int r = e >> 10, c = e & 1023;
        float v;
        if (c < 512) {
            float a = W[r * 512 + c] - W[c * 512 + r];
            v = (c == r ? 1.f : 0.f) + a;
        } else {
            int c2 = c - 512;
            float a = W[r * 512 + c2] - W[c2 * 512 + r];
            v = (c2 == r ? 1.f : 0.f) - a;
        }
        G[e] = v;
    }
    gbar(cnt, gen, 64);

    for (int k = 0; k < 4; k++) {
        int ck = k * 128;
        int nct = (896 - 128 * k) >> 6;

        // phase 1: invert 128x128 diagonal block (block 0, register GJ)
        if (bid == 0) {
            int c0 = t & 63, rg = t >> 6;
            float rgs[16][4];
#pragma unroll
            for (int m = 0; m < 16; m++) {
                int r = rg + 8 * m;
#pragma unroll
                for (int q = 0; q < 4; q++) {
                    int c = c0 + 64 * q;
                    rgs[m][q] = (c < 128) ? G[(size_t)(ck + r) * 1024 + ck + c]
                                          : ((r == c - 128) ? 1.f : 0.f);
                }
            }
            if (rg == 0) {
#pragma unroll
                for (int q = 0; q < 4; q++) sm.inv.prow[0][c0 + 64 * q] = rgs[0][q];
            }
            if (c0 == 0) {
#pragma unroll
                for (int m = 0; m < 16; m++) sm.inv.pcol[0][rg + 8 * m] = rgs[m][0];
            }
            __syncthreads();
            for (int p = 0; p < 128; p++) {
                int buf = p & 1;
                float inv = 1.0f / sm.inv.prow[buf][p];
                float pr[4];
#pragma unroll
                for (int q = 0; q < 4; q++) pr[q] = sm.inv.prow[buf][c0 + 64 * q];
#pragma unroll
                for (int m = 0; m < 16; m++) {
                    int r = rg + 8 * m;
                    if (r == p) {
#pragma unroll
                        for (int q = 0; q < 4; q++) rgs[m][q] = pr[q] * inv;
                    } else {
                        float f = sm.inv.pcol[buf][r] * inv;
#pragma unroll
                        for (int q = 0; q < 4; q++) rgs[m][q] -= f * pr[q];
                    }
                }
                if (p < 127) {
                    int p2 = p + 1, nb = p2 & 1;
                    int mp = p2 >> 3, qp = p2 >> 6;
                    if (rg == (p2 & 7)) {
#pragma unroll
                        for (int m = 0; m < 16; m++)
                            if (m == mp) {
#pragma unroll
                                for (int q = 0; q < 4; q++)
                                    sm.inv.prow[nb][c0 + 64 * q] = rgs[m][q];
                            }
                    }
                    if (c0 == (p2 & 63)) {
#pragma unroll
                        for (int q = 0; q < 4; q++)
                            if (q == qp) {
#pragma unroll
                                for (int m = 0; m < 16; m++)
                                    sm.inv.pcol[nb][rg + 8 * m] = rgs[m][q];
                            }
                    }
                }
                __syncthreads();
            }
#pragma unroll
            for (int m = 0; m < 16; m++) {
                Dinv[(rg + 8 * m) * 128 + c0] = rgs[m][2];
                Dinv[(rg + 8 * m) * 128 + c0 + 64] = rgs[m][3];
            }
        }
        gbar(cnt, gen, 64);

        // phase 2: P = Dinv x G[Rk, active] -> Pbuf[128][896]
        if (bid < nct) {
            int cbase = ck + 128 + bid * 64;
            for (int idx = t; idx < 128 * 64; idx += 512) {
                int r = idx >> 6, c = idx & 63;
                sm.rs.ins[r][c] = G[(size_t)(ck + r) * 1024 + cbase + c];
            }
            int tx = t & 15, ty = t >> 4;
            float acc[4][4];
#pragma unroll
            for (int i = 0; i < 4; i++)
#pragma unroll
                for (int j = 0; j < 4; j++) acc[i][j] = 0.f;
            for (int mc = 0; mc < 4; mc++) {
                __syncthreads();
                for (int idx = t; idx < 128 * 32; idx += 512) {
                    int r = idx >> 5, c = idx & 31;
                    sm.rs.dch[r][c] = Dinv[r * 128 + mc * 32 + c];
                }
                __syncthreads();
                for (int m2 = 0; m2 < 32; m2++) {
                    int mm = mc * 32 + m2;
                    float p0 = sm.rs.ins[mm][tx * 4 + 0], p1 = sm.rs.ins[mm][tx * 4 + 1];
                    float p2 = sm.rs.ins[mm][tx * 4 + 2], p3 = sm.rs.ins[mm][tx * 4 + 3];
#pragma unroll
                    for (int rr = 0; rr < 4; rr++) {
                        float d = sm.rs.dch[ty * 4 + rr][m2];
                        acc[rr][0] += d * p0;
                        acc[rr][1] += d * p1;
                        acc[rr][2] += d * p2;
                        acc[rr][3] += d * p3;
                    }
                }
            }
#pragma unroll
            for (int rr = 0; rr < 4; rr++)
#pragma unroll
                for (int cc = 0; cc < 4; cc++)
                    Pbuf[(ty * 4 + rr) * 896 + bid * 64 + tx * 4 + cc] = acc[rr][cc];
        }
        gbar(cnt, gen, 64);

        // phase 3: trailing update + pivot-row copy (tiles looped over 64 blocks)
        for (int tl = bid; tl < nct * 8; tl += 64) {
            int ct = tl >> 3, rt = tl & 7;
            int cbase = ck + 128 + ct * 64;
            int rb = rt * 64;
            bool pivot = (rb >= ck) && (rb < ck + 128);
            __syncthreads();
            if (pivot) {
                for (int idx = t; idx < 64 * 64; idx += 512) {
                    int r = idx >> 6, c = idx & 63;
                    G[(size_t)(rb + r) * 1024 + cbase + c] =
                        Pbuf[(rb - ck + r) * 896 + ct * 64 + c];
                }
            } else {
                for (int idx = t; idx < 64 * 128; idx += 512) {
                    int r = idx >> 7, c = idx & 127;
                    sm.tr.Lt[r][c] = G[(size_t)(rb + r) * 1024 + ck + c];
                }
                for (int idx = t; idx < 128 * 64; idx += 512) {
                    int r = idx >> 6, c = idx & 63;
                    sm.tr.Pt[r][c] = Pbuf[r * 896 + ct * 64 + c];
                }
                __syncthreads();
                int tx = t & 15, ty = t >> 4;
                float acc[2][4];
#pragma unroll
                for (int i = 0; i < 2; i++)
#pragma unroll
                    for (int j = 0; j < 4; j++) acc[i][j] = 0.f;
                for (int mm = 0; mm < 128; mm++) {
                    float p0 = sm.tr.Pt[mm][tx * 4 + 0], p1 = sm.tr.Pt[mm][tx * 4 + 1];
                    float p2 = sm.tr.Pt[mm][tx * 4 + 2], p3 = sm.tr.Pt[mm][tx * 4 + 3];
                    float l0 = sm.tr.Lt[ty * 2 + 0][mm], l1 = sm.tr.Lt[ty * 2 + 1][mm];
                    acc[0][0] += l0 * p0; acc[0][1] += l0 * p1;
                    acc[0][2] += l0 * p2; acc[0][3] += l0 * p3;
                    acc[1][0] += l1 * p0; acc[1][1] += l1 * p1;
                    acc[1][2] += l1 * p2; acc[1][3] += l1 * p3;
                }
#pragma unroll
                for (int rr = 0; rr < 2; rr++)
#pragma unroll
                    for (int cc = 0; cc < 4; cc++)
                        G[(size_t)(rb + ty * 2 + rr) * 1024 + cbase + tx * 4 + cc] -=
                            acc[rr][cc];
            }
        }
        gbar(cnt, gen, 64);
    }

    // release the heaters (factorization serial work is done; cvtK is parallel)
    if (bid == 0 && t == 0)
        __hip_atomic_store(flag, 1u, __ATOMIC_RELAXED, __HIP_MEMORY_SCOPE_AGENT);

    // phase 4: K (right half of G) -> bf16
    for (int g2 = bid * 512 + t; g2 < 65536; g2 += 64 * 512) {
        int e = g2 * 4;
        int j = e >> 9, i = e & 511;
        const float* src = G + (size_t)j * 1024 + 512 + i;
        float v0 = src[0], v1 = src[1], v2 = src[2], v3 = src[3];
        uint2 pk;
        pk.x = f2bf(v0) | ((unsigned)f2bf(v1) << 16);
        pk.y = f2bf(v2) | ((unsigned)f2bf(v3) << 16);
        *(uint2*)(Kb + j * 512 + i) = pk;
    }
}

// ===========================================================================
// Main GEMM (round-1 proven version): y[b,j,n] = sum_i K[j,i] x[b,i,n].
// Block = all 512 j x 64 n; 8 waves; mfma 16x16x32 bf16; K staged via
// global_load_lds (swizzled), x f32 loaded to regs, converted, ds-written.
// ===========================================================================
#define LDX 40  // padded xt row length (bf16 elems)

__global__ __launch_bounds__(512, 2) void gemm_kernel(const float* __restrict__ x,
                                                      const unsigned short* __restrict__ Kb,
                                                      float* __restrict__ y) {
    __shared__ unsigned short kt[2][512 * 32];  // K tiles: 512 j x 32 i, linear+swizzled
    __shared__ unsigned short xt[2][64 * LDX];  // x tiles: 64 n x 32 i, padded
    int t = threadIdx.x;
    int l = t & 63, w = t >> 6;
    int bx = blockIdx.x;
    int b = bx >> 8;
    int n0 = (bx & 255) << 6;
    const float* xb = x + (size_t)b * CDIM * NSEQ + n0;
    float* yb = y + (size_t)b * CDIM * NSEQ + n0;

    int lr = l & 15;
    int q8 = (l >> 4) * 8;            // k-offset (bf16 elems) of this lane's fragment
    int kidx = q8 ^ ((lr & 3) << 3);  // swizzled k-offset for kt reads

    // per-lane swizzled global source for K staging
    const char* kgl = (const char*)Kb + (size_t)(64 * w + (l >> 2)) * 1024 +
                      (((l & 3) * 16) ^ (((l >> 2) & 3) << 4));

    f32x4 acc[4][4];
#pragma unroll
    for (int i = 0; i < 4; i++)
#pragma unroll
        for (int j = 0; j < 4; j++) acc[i][j] = (f32x4){0.f, 0.f, 0.f, 0.f};

    // prologue: stage s=0 into buffer 0
    {
        unsigned short* kdst = kt[0] + w * 2048;
#pragma unroll
        for (int i = 0; i < 4; i++) gll16(kgl + i * 16384, kdst + i * 512);
        const float* xs = xb + (size_t)(w * 4) * NSEQ + l;
        uint2 pk;
        pk.x = f2bf(xs[0]) | ((unsigned)f2bf(xs[NSEQ]) << 16);
        pk.y = f2bf(xs[2 * NSEQ]) | ((unsigned)f2bf(xs[3 * NSEQ]) << 16);
        *(uint2*)(xt[0] + l * LDX + w * 4) = pk;
    }

    for (int s = 0; s < 16; s++) {
        const unsigned short* ktc = kt[s & 1];
        const unsigned short* xtc = xt[s & 1];
        __syncthreads();  // buf[s&1] fully staged

        // prefetch s+1 early; latency hides under MFMAs
        float v0, v1, v2, v3;
        if (s < 15) {
            unsigned short* kdst = kt[(s + 1) & 1] + w * 2048;
#pragma unroll
            for (int i = 0; i < 4; i++)
                gll16(kgl + (s + 1) * 64 + i * 16384, kdst + i * 512);
            const float* xs = xb + (size_t)((s + 1) * 32 + w * 4) * NSEQ + l;
            v0 = xs[0];
            v1 = xs[NSEQ];
            v2 = xs[2 * NSEQ];
            v3 = xs[3 * NSEQ];
        }

        // compute on buf[s&1]
        short8 af[4], bfr[4];
#pragma unroll
        for (int mt = 0; mt < 4; mt++)
            af[mt] = *(const short8*)(ktc + (w * 64 + mt * 16 + lr) * 32 + kidx);
#pragma unroll
        for (int nt = 0; nt < 4; nt++)
            bfr[nt] = *(const short8*)(xtc + (nt * 16 + lr) * LDX + q8);
#pragma unroll
        for (int mt = 0; mt < 4; mt++)
#pragma unroll
            for (int nt = 0; nt < 4; nt++)
                acc[mt][nt] = __builtin_amdgcn_mfma_f32_16x16x32_bf16(af[mt], bfr[nt],
                                                                      acc[mt][nt], 0, 0, 0);

        // late write of prefetched x into the next buffer
        if (s < 15) {
            uint2 pk;
            pk.x = f2bf(v0) | ((unsigned)f2bf(v1) << 16);
            pk.y = f2bf(v2) | ((unsigned)f2bf(v3) << 16);
            *(uint2*)(xt[(s + 1) & 1] + l * LDX + w * 4) = pk;
        }
    }

    int qr = (l >> 4) * 4;
#pragma unroll
    for (int mt = 0; mt < 4; mt++)
#pragma unroll
        for (int nt = 0; nt < 4; nt++)
#pragma unroll
            for (int r = 0; r < 4; r++)
                yb[(size_t)(w * 64 + mt * 16 + qr + r) * NSEQ + nt * 16 + lr] =
                    acc[mt][nt][r];
}

// ---------------------------------------------------------------------------
extern "C" void kernel_launch(void* const* d_in, const int* in_sizes, int n_in,
                              void* d_out, int out_size, void* d_ws, size_t ws_size,
                              hipStream_t stream) {
    const float* x = (const float*)d_in[0];
    const float* W = (const float*)d_in[1];
    float* y = (float*)d_out;

    float* G = (float*)d_ws;                                         // 2 MB
    float* DINV = (float*)((char*)d_ws + 0x200000);                  // 64 KB
    float* PB = (float*)((char*)d_ws + 0x210000);                    // 448 KB
    unsigned short* KB = (unsigned short*)((char*)d_ws + 0x280000);  // 512 KB
    unsigned* BAR = (unsigned*)((char*)d_ws + 0x300000);             // 64 B

    hipMemsetAsync((char*)d_ws + 0x300000, 0, 64, stream);
    fused_pre_kernel<<<256, 512, 0, stream>>>(W, G, DINV, PB, KB, BAR);
    gemm_kernel<<<4096, 512, 0, stream>>>(x, KB, y);
}